// Round 1
// baseline (65.714 us; speedup 1.0000x reference)
//
#include <hip/hip_runtime.h>
#include <math.h>

// GaussianNLLLoss: out = -mean( c0 + log(normcdf(-lambda*resid/sigma)) - resid^2/(2*sigma2) )
// resid = y_true - y_pred; sigma2 = exp(2*lsv) + exp(2*lsu); lambda = exp(lsu)/exp(lsv)
// Memory-bound: 2 x 134 MB f32 reads, scalar output.

__global__ __launch_bounds__(256) void gnll_kernel(
    const float4* __restrict__ yp, const float4* __restrict__ yt,
    const float* __restrict__ lsv, const float* __restrict__ lsu,
    float* __restrict__ out, int n4, float neg_inv_n)
{
    // Fold scalars into constants (broadcast loads, computed per-thread, negligible)
    const float std_v = __expf(lsv[0]);
    const float std_u = __expf(lsu[0]);
    const float sigma2 = std_v * std_v + std_u * std_u;
    const float sigma  = sqrtf(sigma2);
    const float llamda = std_u / std_v;
    // cdf_arg = -llamda * resid / sigma ; erf arg = cdf_arg / sqrt(2)
    const float karg   = -llamda / sigma * 0.70710678118654752f;  // * resid -> erf arg
    const float c0     = -0.5f * logf(1.57079632679489662f)       // -0.5*log(pi/2)
                         - 0.5f * logf(sigma2);
    const float inv2s2 = 0.5f / sigma2;

    float acc = 0.0f;
    int idx    = blockIdx.x * blockDim.x + threadIdx.x;
    int stride = gridDim.x * blockDim.x;

    for (int i = idx; i < n4; i += stride) {
        float4 p = yp[i];
        float4 t = yt[i];
        float r0 = t.x - p.x;
        float r1 = t.y - p.y;
        float r2 = t.z - p.z;
        float r3 = t.w - p.w;
        float ll0 = logf(0.5f * (1.0f + erff(karg * r0))) - r0 * r0 * inv2s2;
        float ll1 = logf(0.5f * (1.0f + erff(karg * r1))) - r1 * r1 * inv2s2;
        float ll2 = logf(0.5f * (1.0f + erff(karg * r2))) - r2 * r2 * inv2s2;
        float ll3 = logf(0.5f * (1.0f + erff(karg * r3))) - r3 * r3 * inv2s2;
        acc += (ll0 + ll1) + (ll2 + ll3);
        acc += 4.0f * c0;
    }

    // wave64 butterfly reduce
    #pragma unroll
    for (int off = 32; off > 0; off >>= 1)
        acc += __shfl_down(acc, off, 64);

    __shared__ float ws[4];  // 256 threads = 4 waves
    int lane = threadIdx.x & 63;
    int wid  = threadIdx.x >> 6;
    if (lane == 0) ws[wid] = acc;
    __syncthreads();
    if (threadIdx.x == 0) {
        float s = (ws[0] + ws[1]) + (ws[2] + ws[3]);
        atomicAdd(out, s * neg_inv_n);  // device-scope by default on CDNA
    }
}

extern "C" void kernel_launch(void* const* d_in, const int* in_sizes, int n_in,
                              void* d_out, int out_size, void* d_ws, size_t ws_size,
                              hipStream_t stream) {
    const float4* yp = (const float4*)d_in[0];
    const float4* yt = (const float4*)d_in[1];
    const float* lsv = (const float*)d_in[2];
    const float* lsu = (const float*)d_in[3];
    float* out = (float*)d_out;

    long long n = (long long)in_sizes[0];   // 8192*4096 = 33554432, divisible by 4
    int n4 = (int)(n / 4);
    float neg_inv_n = -1.0f / (float)n;

    // Zero the accumulator (graph-capture-safe async memset; harness poisons d_out
    // to 0xAA and does not re-poison between replays).
    hipMemsetAsync(d_out, 0, sizeof(float), stream);

    int block = 256;
    int grid  = 2048;  // 256 CU x 8 blocks, grid-stride covers 8.4M float4s
    gnll_kernel<<<grid, block, 0, stream>>>(yp, yt, lsv, lsu, out, n4, neg_inv_n);
}

// Round 2
// 63.977 us; speedup vs baseline: 1.0272x; 1.0272x over previous
//
#include <hip/hip_runtime.h>
#include <math.h>

// GaussianNLLLoss: out = -mean( c0 + log(normcdf(-lambda*resid/sigma)) - resid^2/(2*sigma2) )
// resid = y_true - y_pred; sigma2 = exp(2*lsv) + exp(2*lsu); lambda = exp(lsu)/exp(lsv)
// Memory-bound: 2 x 134 MB f32 reads, scalar output. Floor = 268MB / 6.3TB/s ~= 43us.
//
// R2: replace libm erff+logf (~60 VALU ops/elem, accurate div + poly fixups) with
// A&S 7.1.26 erf (1 v_rcp + 1 v_exp + 5 FMA, |err|<1.5e-7) + __logf (v_log_f32).
// erf-arg range is |x| <~ 2.5 for these inputs -> approximation error in the mean
// is orders of magnitude below the 3.9e-2 threshold.

// log(0.5*(1+erf(x))) via Abramowitz-Stegun 7.1.26 + fast log
__device__ __forceinline__ float fast_log_ncdf_erfarg(float x) {
    float ax = fabsf(x);
    float t  = __builtin_amdgcn_rcpf(fmaf(0.3275911f, ax, 1.0f));  // v_rcp_f32
    float p  = fmaf(t, 1.061405429f, -1.453152027f);
    p = fmaf(t, p, 1.421413741f);
    p = fmaf(t, p, -0.284496736f);
    p = fmaf(t, p, 0.254829592f);
    p *= t;
    float e  = __expf(-ax * ax);                 // v_exp_f32 (+1 mul)
    float ea = fmaf(-p, e, 1.0f);                // erf(|x|)
    float ev = copysignf(ea, x);                 // erf(x)
    return __logf(fmaf(0.5f, ev, 0.5f));         // log(0.5*(1+erf)) via v_log_f32
}

__global__ __launch_bounds__(256) void gnll_kernel(
    const float4* __restrict__ yp, const float4* __restrict__ yt,
    const float* __restrict__ lsv, const float* __restrict__ lsu,
    float* __restrict__ out, int n4, float neg_inv_n)
{
    // Fold scalars into constants (broadcast loads, negligible)
    const float std_v  = __expf(lsv[0]);
    const float std_u  = __expf(lsu[0]);
    const float sigma2 = std_v * std_v + std_u * std_u;
    const float sigma  = sqrtf(sigma2);
    const float llamda = std_u / std_v;
    const float karg   = -llamda / sigma * 0.70710678118654752f;  // * resid -> erf arg
    const float c0     = -0.5f * logf(1.57079632679489662f)       // -0.5*log(pi/2)
                         - 0.5f * logf(sigma2);
    const float inv2s2 = 0.5f / sigma2;

    float acc = 0.0f;
    int   cnt = 0;
    int idx    = blockIdx.x * blockDim.x + threadIdx.x;
    int stride = gridDim.x * blockDim.x;

    for (int i = idx; i < n4; i += stride) {
        float4 p = yp[i];
        float4 t = yt[i];
        float r0 = t.x - p.x;
        float r1 = t.y - p.y;
        float r2 = t.z - p.z;
        float r3 = t.w - p.w;
        float ll0 = fast_log_ncdf_erfarg(karg * r0) - r0 * r0 * inv2s2;
        float ll1 = fast_log_ncdf_erfarg(karg * r1) - r1 * r1 * inv2s2;
        float ll2 = fast_log_ncdf_erfarg(karg * r2) - r2 * r2 * inv2s2;
        float ll3 = fast_log_ncdf_erfarg(karg * r3) - r3 * r3 * inv2s2;
        acc += (ll0 + ll1) + (ll2 + ll3);
        cnt += 4;
    }
    acc = fmaf((float)cnt, c0, acc);  // add c0 once per element, outside the loop

    // wave64 butterfly reduce
    #pragma unroll
    for (int off = 32; off > 0; off >>= 1)
        acc += __shfl_down(acc, off, 64);

    __shared__ float ws[4];  // 256 threads = 4 waves
    int lane = threadIdx.x & 63;
    int wid  = threadIdx.x >> 6;
    if (lane == 0) ws[wid] = acc;
    __syncthreads();
    if (threadIdx.x == 0) {
        float s = (ws[0] + ws[1]) + (ws[2] + ws[3]);
        atomicAdd(out, s * neg_inv_n);  // device-scope by default on CDNA
    }
}

extern "C" void kernel_launch(void* const* d_in, const int* in_sizes, int n_in,
                              void* d_out, int out_size, void* d_ws, size_t ws_size,
                              hipStream_t stream) {
    const float4* yp = (const float4*)d_in[0];
    const float4* yt = (const float4*)d_in[1];
    const float* lsv = (const float*)d_in[2];
    const float* lsu = (const float*)d_in[3];
    float* out = (float*)d_out;

    long long n = (long long)in_sizes[0];   // 8192*4096 = 33554432, divisible by 4
    int n4 = (int)(n / 4);
    float neg_inv_n = -1.0f / (float)n;

    hipMemsetAsync(d_out, 0, sizeof(float), stream);

    int block = 256;
    int grid  = 2048;  // 256 CU x 8 blocks, grid-stride covers 8.4M float4s
    gnll_kernel<<<grid, block, 0, stream>>>(yp, yt, lsv, lsu, out, n4, neg_inv_n);
}

// Round 3
// 60.275 us; speedup vs baseline: 1.0902x; 1.0614x over previous
//
#include <hip/hip_runtime.h>
#include <math.h>

// GaussianNLLLoss: out = -mean( c0 + log(normcdf(-lambda*resid/sigma)) - resid^2/(2*sigma2) )
// Memory-bound target: 268 MB reads. R3: batch 8 loads (4 yp + 4 yt float4,
// 8KB/wave) before computing -> 4x MLP per wave, 1/4 the vmcnt wait points.
// R2 lesson: latency-bound (VALUBusy 27% = C/(L+C)), not VALU-bound.

__device__ __forceinline__ float fast_log_ncdf_erfarg(float x) {
    float ax = fabsf(x);
    float t  = __builtin_amdgcn_rcpf(fmaf(0.3275911f, ax, 1.0f));  // v_rcp_f32
    float p  = fmaf(t, 1.061405429f, -1.453152027f);
    p = fmaf(t, p, 1.421413741f);
    p = fmaf(t, p, -0.284496736f);
    p = fmaf(t, p, 0.254829592f);
    p *= t;
    float e  = __expf(-ax * ax);                 // v_exp_f32
    float ea = fmaf(-p, e, 1.0f);                // erf(|x|)
    float ev = copysignf(ea, x);                 // erf(x)
    return __logf(fmaf(0.5f, ev, 0.5f));         // log(0.5*(1+erf))
}

__global__ __launch_bounds__(256) void gnll_kernel(
    const float4* __restrict__ yp, const float4* __restrict__ yt,
    const float* __restrict__ lsv, const float* __restrict__ lsu,
    float* __restrict__ out, int n4, float neg_inv_n)
{
    const float std_v  = __expf(lsv[0]);
    const float std_u  = __expf(lsu[0]);
    const float sigma2 = std_v * std_v + std_u * std_u;
    const float sigma  = sqrtf(sigma2);
    const float llamda = std_u / std_v;
    const float karg   = -llamda / sigma * 0.70710678118654752f;
    const float c0     = -0.5f * logf(1.57079632679489662f)
                         - 0.5f * logf(sigma2);
    const float inv2s2 = 0.5f / sigma2;

    float acc = 0.0f;
    int   cnt = 0;
    const int tid      = blockIdx.x * blockDim.x + threadIdx.x;
    const int nthreads = gridDim.x * blockDim.x;

    // Full groups of 4 float4s per thread: issue all 8 loads, then compute.
    const int ngroups = n4 / (nthreads * 4);
    for (int g = 0; g < ngroups; ++g) {
        const int base = g * nthreads * 4 + tid;
        float4 p0 = yp[base];
        float4 p1 = yp[base + nthreads];
        float4 p2 = yp[base + 2 * nthreads];
        float4 p3 = yp[base + 3 * nthreads];
        float4 t0 = yt[base];
        float4 t1 = yt[base + nthreads];
        float4 t2 = yt[base + 2 * nthreads];
        float4 t3 = yt[base + 3 * nthreads];

        float r[16];
        r[0]=t0.x-p0.x; r[1]=t0.y-p0.y; r[2]=t0.z-p0.z; r[3]=t0.w-p0.w;
        r[4]=t1.x-p1.x; r[5]=t1.y-p1.y; r[6]=t1.z-p1.z; r[7]=t1.w-p1.w;
        r[8]=t2.x-p2.x; r[9]=t2.y-p2.y; r[10]=t2.z-p2.z; r[11]=t2.w-p2.w;
        r[12]=t3.x-p3.x; r[13]=t3.y-p3.y; r[14]=t3.z-p3.z; r[15]=t3.w-p3.w;

        float s = 0.0f;
        #pragma unroll
        for (int j = 0; j < 16; ++j)
            s += fast_log_ncdf_erfarg(karg * r[j]) - r[j] * r[j] * inv2s2;
        acc += s;
        cnt += 16;
    }

    // Tail (none for the bench shape, but stay general)
    for (int i = ngroups * nthreads * 4 + tid; i < n4; i += nthreads) {
        float4 p = yp[i];
        float4 t = yt[i];
        float rr[4] = {t.x-p.x, t.y-p.y, t.z-p.z, t.w-p.w};
        #pragma unroll
        for (int j = 0; j < 4; ++j)
            acc += fast_log_ncdf_erfarg(karg * rr[j]) - rr[j] * rr[j] * inv2s2;
        cnt += 4;
    }

    acc = fmaf((float)cnt, c0, acc);

    // wave64 butterfly reduce
    #pragma unroll
    for (int off = 32; off > 0; off >>= 1)
        acc += __shfl_down(acc, off, 64);

    __shared__ float ws[4];
    int lane = threadIdx.x & 63;
    int wid  = threadIdx.x >> 6;
    if (lane == 0) ws[wid] = acc;
    __syncthreads();
    if (threadIdx.x == 0) {
        float s = (ws[0] + ws[1]) + (ws[2] + ws[3]);
        atomicAdd(out, s * neg_inv_n);
    }
}

extern "C" void kernel_launch(void* const* d_in, const int* in_sizes, int n_in,
                              void* d_out, int out_size, void* d_ws, size_t ws_size,
                              hipStream_t stream) {
    const float4* yp = (const float4*)d_in[0];
    const float4* yt = (const float4*)d_in[1];
    const float* lsv = (const float*)d_in[2];
    const float* lsu = (const float*)d_in[3];
    float* out = (float*)d_out;

    long long n = (long long)in_sizes[0];   // 33554432, divisible by 4
    int n4 = (int)(n / 4);
    float neg_inv_n = -1.0f / (float)n;

    hipMemsetAsync(d_out, 0, sizeof(float), stream);

    int block = 256;
    int grid  = 2048;  // 524288 threads -> 4 groups of 4 float4 each, no tail
    gnll_kernel<<<grid, block, 0, stream>>>(yp, yt, lsv, lsu, out, n4, neg_inv_n);
}

// Round 4
// 58.029 us; speedup vs baseline: 1.1324x; 1.0387x over previous
//
#include <hip/hip_runtime.h>
#include <math.h>

// GaussianNLLLoss: out = -mean( c0 + log(normcdf(-lambda*resid/sigma)) - resid^2/(2*sigma2) )
// R4: register-level double-buffered software pipeline. R3 lesson: compiler did
// NOT keep prefetch in flight (VGPR=32 => no pipelining); each group drained
// vmcnt(0) before compute -> exposed ~900cyc latency per group. Now: issue next
// group's 8 dwordx4 into alternate named register buffer BEFORE computing the
// current group, so loads fly under the ~2000-cycle compute phase.

__device__ __forceinline__ float ll_elem(float r, float karg, float nk2, float inv2s2) {
    float r2 = r * r;
    float x  = karg * r;
    float ax = fabsf(x);
    float t  = __builtin_amdgcn_rcpf(fmaf(0.3275911f, ax, 1.0f));  // v_rcp_f32
    float p  = fmaf(t, 1.061405429f, -1.453152027f);
    p = fmaf(t, p, 1.421413741f);
    p = fmaf(t, p, -0.284496736f);
    p = fmaf(t, p, 0.254829592f);
    p *= t;
    float e  = __expf(nk2 * r2);                 // exp(-x^2), reusing r^2
    float ea = fmaf(-p, e, 1.0f);                // erf(|x|)  (A&S 7.1.26, |err|<1.5e-7)
    float ev = copysignf(ea, x);                 // erf(x)
    return __logf(fmaf(0.5f, ev, 0.5f)) - r2 * inv2s2;  // log(ncdf) - r^2/(2s2)
}

__global__ __launch_bounds__(256) void gnll_kernel(
    const float4* __restrict__ yp, const float4* __restrict__ yt,
    const float* __restrict__ lsv, const float* __restrict__ lsu,
    float* __restrict__ out, int n4, float neg_inv_n)
{
    const float std_v  = __expf(lsv[0]);
    const float std_u  = __expf(lsu[0]);
    const float sigma2 = std_v * std_v + std_u * std_u;
    const float sigma  = sqrtf(sigma2);
    const float llamda = std_u / std_v;
    const float karg   = -llamda / sigma * 0.70710678118654752f;  // *r -> erf arg
    const float nk2    = -karg * karg;                            // *r^2 -> -x^2
    const float c0     = -0.5f * logf(1.57079632679489662f)
                         - 0.5f * logf(sigma2);
    const float inv2s2 = 0.5f / sigma2;

    float acc = 0.0f;
    int   cnt = 0;
    const int tid = blockIdx.x * blockDim.x + threadIdx.x;
    const int nth = gridDim.x * blockDim.x;

    float4 pA0, pA1, pA2, pA3, tA0, tA1, tA2, tA3;
    float4 pB0, pB1, pB2, pB3, tB0, tB1, tB2, tB3;

#define LOAD_A(g) { int b_ = (g) * nth * 4 + tid;                                   \
    pA0 = yp[b_]; pA1 = yp[b_ + nth]; pA2 = yp[b_ + 2*nth]; pA3 = yp[b_ + 3*nth];   \
    tA0 = yt[b_]; tA1 = yt[b_ + nth]; tA2 = yt[b_ + 2*nth]; tA3 = yt[b_ + 3*nth]; }
#define LOAD_B(g) { int b_ = (g) * nth * 4 + tid;                                   \
    pB0 = yp[b_]; pB1 = yp[b_ + nth]; pB2 = yp[b_ + 2*nth]; pB3 = yp[b_ + 3*nth];   \
    tB0 = yt[b_]; tB1 = yt[b_ + nth]; tB2 = yt[b_ + 2*nth]; tB3 = yt[b_ + 3*nth]; }
#define COMP1(P, T) { float s_ =                                                    \
      ll_elem(T.x - P.x, karg, nk2, inv2s2) + ll_elem(T.y - P.y, karg, nk2, inv2s2) \
    + ll_elem(T.z - P.z, karg, nk2, inv2s2) + ll_elem(T.w - P.w, karg, nk2, inv2s2);\
    acc += s_; }
#define COMP_A { COMP1(pA0, tA0) COMP1(pA1, tA1) COMP1(pA2, tA2) COMP1(pA3, tA3) cnt += 16; }
#define COMP_B { COMP1(pB0, tB0) COMP1(pB1, tB1) COMP1(pB2, tB2) COMP1(pB3, tB3) cnt += 16; }

    const int ngroups = n4 / (nth * 4);   // 4 for the bench shape
    if (ngroups > 0) {
        LOAD_A(0)
        int g = 0;
        for (; g + 2 < ngroups; g += 2) {
            LOAD_B(g + 1)   // in flight under COMP_A
            COMP_A
            LOAD_A(g + 2)   // in flight under COMP_B
            COMP_B
        }
        if (g + 1 < ngroups) {
            LOAD_B(g + 1)
            COMP_A
            COMP_B
        } else {
            COMP_A
        }
    }

    // Tail positions (none for the bench shape)
    for (int i = ngroups * nth * 4 + tid; i < n4; i += nth) {
        float4 p = yp[i];
        float4 t = yt[i];
        acc += ll_elem(t.x - p.x, karg, nk2, inv2s2)
             + ll_elem(t.y - p.y, karg, nk2, inv2s2)
             + ll_elem(t.z - p.z, karg, nk2, inv2s2)
             + ll_elem(t.w - p.w, karg, nk2, inv2s2);
        cnt += 4;
    }

    acc = fmaf((float)cnt, c0, acc);

    // wave64 butterfly reduce
    #pragma unroll
    for (int off = 32; off > 0; off >>= 1)
        acc += __shfl_down(acc, off, 64);

    __shared__ float ws[4];
    int lane = threadIdx.x & 63;
    int wid  = threadIdx.x >> 6;
    if (lane == 0) ws[wid] = acc;
    __syncthreads();
    if (threadIdx.x == 0) {
        float s = (ws[0] + ws[1]) + (ws[2] + ws[3]);
        atomicAdd(out, s * neg_inv_n);
    }
}

extern "C" void kernel_launch(void* const* d_in, const int* in_sizes, int n_in,
                              void* d_out, int out_size, void* d_ws, size_t ws_size,
                              hipStream_t stream) {
    const float4* yp = (const float4*)d_in[0];
    const float4* yt = (const float4*)d_in[1];
    const float* lsv = (const float*)d_in[2];
    const float* lsu = (const float*)d_in[3];
    float* out = (float*)d_out;

    long long n = (long long)in_sizes[0];   // 33554432, divisible by 4
    int n4 = (int)(n / 4);
    float neg_inv_n = -1.0f / (float)n;

    hipMemsetAsync(d_out, 0, sizeof(float), stream);

    int block = 256;
    int grid  = 2048;  // 524288 threads -> ngroups=4, no tail
    gnll_kernel<<<grid, block, 0, stream>>>(yp, yt, lsv, lsu, out, n4, neg_inv_n);
}